// Round 2
// baseline (915.223 us; speedup 1.0000x reference)
//
#include <hip/hip_runtime.h>
#include <hip/hip_cooperative_groups.h>

// R2: single cooperative mega-kernel. Timed window = ~670us harness poison fills
// + ~120us ours; attack ours: 10 dispatches -> 1 (5 grid.sync), nz lists in LDS
// for the whole kernel, c_i = W_ih*ec_i + b_ih held in REGISTERS across layers
// (C/EC buffers deleted), layer0 reads input h directly, layer3 output stays in
// LDS for readout. Predicted dur 789 -> ~715-745.

namespace cg = cooperative_groups;

__device__ __forceinline__ float sigm(float x){ return 1.f / (1.f + __expf(-x)); }

constexpr int N = 1024, CAP = 192;
constexpr int NB = 256, NT = 384;

// workspace layout (float offsets)
constexpr int OFF_WT_ME   = 0;                        // [f][d] 128x128
constexpr int OFF_WT_IH   = OFF_WT_ME   + 128*128;    // [f][o] 128x384
constexpr int OFF_WT_HH   = OFF_WT_IH   + 128*384;    // [f][o] 128x384
constexpr int OFF_WT_GATE = OFF_WT_HH   + 128*384;    // [f][c] 256x128
constexpr int OFF_WT_OUT  = OFF_WT_GATE + 256*128;    // [f][c] 256x128
constexpr int OFF_WT_FC   = OFF_WT_OUT  + 256*128;    // [c][o] 256x128
constexpr int OFF_EE      = OFF_WT_FC   + 256*128;    // 128
constexpr int OFF_GV      = OFF_EE + 128;             // 128 (zeroed in prep)
constexpr int OFF_WCT     = OFF_GV + 128;             // [f][o] 128x384 = (W_ih*W_mh)^T
constexpr int OFF_HA      = OFF_WCT + 128*384;        // N*128 (h ping)
constexpr int OFF_HB      = OFF_HA  + N*128;          // N*128 (h pong)

// prep segment boundaries (transposes laid out first, contiguously)
constexpr int PT0 = OFF_WT_IH, PT1 = OFF_WT_HH, PT2 = OFF_WT_GATE, PT3 = OFF_WT_OUT,
              PT4 = OFF_WT_FC, PT5 = OFF_EE, PT6 = OFF_GV, PT7 = OFF_WCT; // prep end

__global__ __launch_bounds__(NT, 1)
void k_mega(const float* __restrict__ h,    const float* __restrict__ e,
            const float* __restrict__ adj,
            const float* __restrict__ w_mh, const float* __restrict__ w_me,
            const float* __restrict__ b_msg,
            const float* __restrict__ w_ih, const float* __restrict__ w_hh,
            const float* __restrict__ b_ih, const float* __restrict__ b_hh,
            const float* __restrict__ w_gate, const float* __restrict__ b_gate,
            const float* __restrict__ w_out,  const float* __restrict__ b_out,
            const float* __restrict__ w_emb,  const float* __restrict__ edge,
            const float* __restrict__ w_fc,   const float* __restrict__ b_fc,
            float* __restrict__ out, float* ws){
  cg::grid_group grid = cg::this_grid();
  const int t = threadIdx.x, b = blockIdx.x, i0 = b * 4;

  __shared__ int   idxs[4][CAP];          // persist: nz lists for own 4 rows
  __shared__ float vals[4][CAP];
  __shared__ int   cnta[4];
  __shared__ int   cnt_cur;
  __shared__ float ea_sh[4][128];         // phase A -> B
  __shared__ float red_sh[6*128];
  __shared__ float ih_sh[3][128];
  __shared__ float ec_sh[4][128];
  __shared__ float hs_sh[4][128], h_sh[4][128];
  __shared__ float sr_sh[4][128], sz_sh[4][128], gn_sh[4][128], hn_sh[4][128];

  // ---------- Phase A1: weight transposes + ee + gv zero (grid-stride) ----------
  for (int idx = b*NT + t; idx < PT7; idx += NB*NT){
    if (idx < PT0)      { int k = idx;       int f = k >> 7, d = k & 127; ws[idx] = w_me[d*128 + f]; }
    else if (idx < PT1) { int k = idx - PT0; int f = k / 384, o = k % 384; ws[idx] = w_ih[o*128 + f]; }
    else if (idx < PT2) { int k = idx - PT1; int f = k / 384, o = k % 384; ws[idx] = w_hh[o*128 + f]; }
    else if (idx < PT3) { int k = idx - PT2; int f = k >> 7, c = k & 127; ws[idx] = w_gate[c*256 + f]; }
    else if (idx < PT4) { int k = idx - PT3; int f = k >> 7, c = k & 127; ws[idx] = w_out[c*256 + f]; }
    else if (idx < PT5) { int k = idx - PT4; int c = k >> 7, o = k & 127; ws[idx] = w_fc[o*256 + c]; }
    else if (idx < PT6) { int c = idx - PT5; float a = 0.f;
                          for (int q = 0; q < 5; ++q) a += w_emb[c*5 + q] * edge[q];
                          ws[idx] = a; }
    else                { ws[idx] = 0.f; }  // gv accumulator
  }

  // ---------- Phase A2: WCT[f][o] = sum_d w_ih[o,d] * w_mh[d,f] ----------
  if (b < 128){
    const int g = t >> 7, f = t & 127, o = b*3 + g;   // 128 blocks x 3 outputs = 384
    ih_sh[g][f] = w_ih[o*128 + f];
    __syncthreads();
    float acc = 0.f;
    for (int d = 0; d < 128; ++d) acc += ih_sh[g][d] * w_mh[d*128 + f];
    ws[OFF_WCT + f*384 + o] = acc;
  }

  // ---------- Phase A3: adj scan + e-aggregate for own rows ----------
  const int lane = t & 63, wv = t >> 6;   // 6 waves
  for (int n = 0; n < 4; ++n){
    const int i = i0 + n;
    if (t == 0) cnt_cur = 0;
    __syncthreads();
    const float* arow = adj + (size_t)i * N;
    for (int j = t; j < N; j += NT){
      float v = arow[j];
      if (v != 0.f){
        int p = atomicAdd(&cnt_cur, 1);
        if (p < CAP){ idxs[n][p] = j; vals[n][p] = v; }
      }
    }
    __syncthreads();
    const int cnt = min(cnt_cur, CAP);
    if (t == 0) cnta[n] = cnt;
    float ax = 0.f, ay = 0.f;
    const float* eb = e + ((size_t)i << 17);   // i*1024*128
    for (int k = wv; k < cnt; k += 6){
      int j = idxs[n][k]; float v = vals[n][k];
      float2 uu = *(const float2*)(eb + (size_t)j*128 + 2*lane);
      ax += v * uu.x;
      ay += v * uu.y;
    }
    red_sh[wv*128 + 2*lane]     = ax;
    red_sh[wv*128 + 2*lane + 1] = ay;
    __syncthreads();
    if (t < 128){
      float s = red_sh[t];
      #pragma unroll
      for (int w = 1; w < 6; ++w) s += red_sh[w*128 + t];
      ea_sh[n][t] = s;
    }
    __syncthreads();
  }
  grid.sync();   // sync 1: transposes + WCT visible

  // ---------- Phase B: ec (LDS only) + cv = W_ih*ec + b_ih (registers) ----------
  {
    const float* wT = ws + OFF_WT_ME;
    for (int idx = t; idx < 512; idx += NT){
      const int n = idx >> 7, d = idx & 127;
      float acc = 0.f;
      for (int f = 0; f < 128; ++f) acc += ea_sh[n][f] * wT[f*128 + d];
      ec_sh[n][d] = acc + b_msg[d];
    }
  }
  __syncthreads();
  float cv[4];
  {
    const float* wi_ = ws + OFF_WT_IH;
    float a0=0.f, a1=0.f, a2=0.f, a3=0.f;
    for (int f = 0; f < 128; ++f){
      const float w = wi_[f*384 + t];
      a0 += w*ec_sh[0][f]; a1 += w*ec_sh[1][f]; a2 += w*ec_sh[2][f]; a3 += w*ec_sh[3][f];
    }
    const float bi = b_ih[t];
    cv[0]=a0+bi; cv[1]=a1+bi; cv[2]=a2+bi; cv[3]=a3+bi;
  }
  const float bh = b_hh[t];

  // ---------- Layers: hs = A*h_src, gi = WC*hs + cv, gh = Whh*h + bh, GRU ----------
  float* hA = ws + OFF_HA;
  float* hB = ws + OFF_HB;
  const float* wc_ = ws + OFF_WCT;
  const float* wh_ = ws + OFF_WT_HH;

  for (int l = 0; l < 4; ++l){
    const float* src = (l == 0) ? h : ((l & 1) ? hA : hB);
    float* dst = (l & 1) ? hB : hA;    // l0->hA, l1->hB, l2->hA, l3->(LDS)
    for (int idx = t; idx < 512; idx += NT){
      const int n = idx >> 7, c = idx & 127;
      h_sh[n][c] = src[(size_t)(i0+n)*128 + c];
      float a = 0.f;
      const int cn = cnta[n];
      for (int k = 0; k < cn; ++k) a += vals[n][k] * src[(size_t)idxs[n][k]*128 + c];
      hs_sh[n][c] = a;
    }
    __syncthreads();
    float ag[4] = {}, ah[4] = {};
    for (int f = 0; f < 128; ++f){
      const float wi = wc_[f*384 + t], wh = wh_[f*384 + t];
      #pragma unroll
      for (int n = 0; n < 4; ++n){ ag[n] += wi*hs_sh[n][f]; ah[n] += wh*h_sh[n][f]; }
    }
    if (t < 128){
      #pragma unroll
      for (int n = 0; n < 4; ++n) sr_sh[n][t] = ag[n] + cv[n] + ah[n] + bh;
    } else if (t < 256){
      const int c = t - 128;
      #pragma unroll
      for (int n = 0; n < 4; ++n) sz_sh[n][c] = ag[n] + cv[n] + ah[n] + bh;
    } else {
      const int c = t - 256;
      #pragma unroll
      for (int n = 0; n < 4; ++n){ gn_sh[n][c] = ag[n] + cv[n]; hn_sh[n][c] = ah[n] + bh; }
    }
    __syncthreads();
    for (int idx = t; idx < 512; idx += NT){
      const int n = idx >> 7, c = idx & 127;
      float r  = sigm(sr_sh[n][c]);
      float z  = sigm(sz_sh[n][c]);
      float nn = tanhf(gn_sh[n][c] + r * hn_sh[n][c]);
      float hv = (1.f - z) * nn + z * h_sh[n][c];
      if (l < 3) dst[(size_t)(i0+n)*128 + c] = hv;
      else       hs_sh[n][c] = hv;          // final h stays in LDS for readout
    }
    if (l < 3) grid.sync();   // syncs 2,3,4 (cross-block gather next layer)
    else       __syncthreads();
  }

  // ---------- Readout: own 4 nodes; hcur in hs_sh, h0 from input ----------
  for (int idx = t; idx < 512; idx += NT){
    const int n = idx >> 7, c = idx & 127;
    h_sh[n][c] = h[(size_t)(i0+n)*128 + c];
  }
  __syncthreads();
  {
    const float* wg_ = ws + OFF_WT_GATE;
    const float* wo_ = ws + OFF_WT_OUT;
    if (t < 256){
      const int c = t & 127;
      const float* wm = (t < 128) ? wg_ : wo_;   // group 0: gate proj, group 1: out proj
      float a[4] = {};
      for (int f = 0; f < 128; ++f){
        const float w0 = wm[f*128 + c], w1 = wm[(128+f)*128 + c];
        #pragma unroll
        for (int n = 0; n < 4; ++n) a[n] += hs_sh[n][f]*w0 + h_sh[n][f]*w1;
      }
      if (t < 128){
        #pragma unroll
        for (int n = 0; n < 4; ++n) sz_sh[n][c] = a[n];
      } else {
        #pragma unroll
        for (int n = 0; n < 4; ++n) gn_sh[n][c] = a[n];
      }
    }
  }
  __syncthreads();
  if (t < 128){
    const float bg = b_gate[t], bo = b_out[t];
    float s = 0.f;
    #pragma unroll
    for (int n = 0; n < 4; ++n) s += sigm(sz_sh[n][t] + bg) * tanhf(gn_sh[n][t] + bo);
    atomicAdd(ws + OFF_GV + t, s);
  }
  grid.sync();   // sync 5: gv complete

  // ---------- FC: block 0 only ----------
  if (b == 0 && t < 128){
    const float* wT = ws + OFF_WT_FC;
    const float* gv = ws + OFF_GV;
    const float* ee = ws + OFF_EE;
    float acc = b_fc[t];
    for (int c = 0; c < 128; ++c) acc += gv[c] * wT[c*128 + t];
    for (int c = 0; c < 128; ++c) acc += ee[c] * wT[(128 + c)*128 + t];
    out[t] = acc;
  }
}

extern "C" void kernel_launch(void* const* d_in, const int* in_sizes, int n_in,
                              void* d_out, int out_size, void* d_ws, size_t ws_size,
                              hipStream_t stream){
  const float* h      = (const float*)d_in[0];
  const float* e      = (const float*)d_in[1];
  const float* adj    = (const float*)d_in[2];
  const float* edge   = (const float*)d_in[3];
  const float* w_mh   = (const float*)d_in[4];
  const float* w_me   = (const float*)d_in[5];
  const float* b_msg  = (const float*)d_in[6];
  const float* w_ih   = (const float*)d_in[7];
  const float* w_hh   = (const float*)d_in[8];
  const float* b_ih   = (const float*)d_in[9];
  const float* b_hh   = (const float*)d_in[10];
  const float* w_gate = (const float*)d_in[11];
  const float* b_gate = (const float*)d_in[12];
  const float* w_out  = (const float*)d_in[13];
  const float* b_out  = (const float*)d_in[14];
  const float* w_emb  = (const float*)d_in[15];
  const float* w_fc   = (const float*)d_in[16];
  const float* b_fc   = (const float*)d_in[17];
  float* outp = (float*)d_out;
  float* ws   = (float*)d_ws;

  void* args[] = { (void*)&h, (void*)&e, (void*)&adj,
                   (void*)&w_mh, (void*)&w_me, (void*)&b_msg,
                   (void*)&w_ih, (void*)&w_hh, (void*)&b_ih, (void*)&b_hh,
                   (void*)&w_gate, (void*)&b_gate, (void*)&w_out, (void*)&b_out,
                   (void*)&w_emb, (void*)&edge, (void*)&w_fc, (void*)&b_fc,
                   (void*)&outp, (void*)&ws };
  hipLaunchCooperativeKernel((void*)k_mega, dim3(NB), dim3(NT), args, 0, stream);
}